// Round 10
// baseline (414.680 us; speedup 1.0000x reference)
//
#include <hip/hip_runtime.h>
#include <stdint.h>
#include <stddef.h>

// Problem constants (B, F, D) = (1024, 16, 64); P = 120
constexpr int NB = 1024;
constexpr int NF = 16;
constexpr int ND = 64;
constexpr int NP = 120;
constexpr int KD = ND * ND;          // 4096 contraction length per pair
constexpr int OUT_STRIDE = NP * ND;  // 7680 floats per batch row

constexpr int BM = 256;              // batch rows per block
constexpr int NS = 32;               // stages; each stage = 2 a-columns (BK = 128)
// 8 waves: 4 m-groups (64 rows) x 2 n-groups (32 cols); 32x32x16 MFMA.
// W staged in LDS in MFMA-FRAGMENT order [col][slab=2kc+kh][n][8] -> both
// ds_write and ds_read are lane-contiguous (conflict-free, no swizzle).
// Each stage runs as TWO double-barrier-sandwiched 8-MFMA clusters (8-phase port).

using floatx4  = __attribute__((ext_vector_type(4))) float;
using floatx16 = __attribute__((ext_vector_type(16))) float;
using half8    = __attribute__((ext_vector_type(8))) _Float16;
using half2v   = __attribute__((ext_vector_type(2))) _Float16;
using fp16x2   = __attribute__((ext_vector_type(2))) __fp16;   // cvt_pkrtz return type
using uint4v   = __attribute__((ext_vector_type(4))) uint32_t;

constexpr int WBUF = 8192;   // u16 per W buffer: 2 cols x 8 slabs x 64 n x 8 = 16 KiB

__device__ __forceinline__ half2v pkh2(float f0, float f1) {
    fp16x2 h = __builtin_amdgcn_cvt_pkrtz(f0, f1);
    return __builtin_bit_cast(half2v, h);
}
__device__ __forceinline__ uint32_t pk16(float f0, float f1) {
    fp16x2 h = __builtin_amdgcn_cvt_pkrtz(f0, f1);
    return __builtin_bit_cast(uint32_t, h);
}
__device__ __forceinline__ uint16_t f16bits(float f) {
    return __builtin_bit_cast(uint16_t, (_Float16)f);   // RNE scalar cvt
}
__device__ __forceinline__ half2v dupperm(uint32_t w, uint32_t sel) {
    return __builtin_bit_cast(half2v, __builtin_amdgcn_perm(w, w, sel));
}

__device__ __forceinline__ void wait_lgkm0() {
    asm volatile("s_waitcnt lgkmcnt(0)" ::: "memory");
}
__device__ __forceinline__ void barrier_only() {   // no vmcnt drain: prefetch stays in flight
    asm volatile("" ::: "memory");
    __builtin_amdgcn_s_barrier();
    asm volatile("" ::: "memory");
}

__global__ __launch_bounds__(512, 4)
void outer_kernel(const float* __restrict__ x, const float* __restrict__ W,
                  const float* __restrict__ bias, float* __restrict__ out)
{
    // xi^T fp16, [a][wm][r32*2 + mt] -> one b32 per (a) per wave, quad-broadcast
    __shared__ uint16_t lds_xit[ND * BM];   // 32,768 B
    __shared__ uint16_t lds_w[2 * WBUF];    // W stage dbuf (frag layout): 32,768 B; total 64 KB

    const int p  = blockIdx.x;        // pair 0..119
    const int b0 = blockIdx.y * BM;   // batch tile origin

    // triu_indices(16, k=1) order
    int icol = 0, rem = p;
    while (rem >= NF - 1 - icol) { rem -= NF - 1 - icol; ++icol; }
    const int jcol = icol + 1 + rem;

    const int t    = threadIdx.x;
    const int wave = t >> 6;
    const int lane = t & 63;
    const int r32  = lane & 31;
    const int kh   = lane >> 5;       // k-half (0/1) of the 32x32x16 fragment
    const int wm   = wave & 3;        // m-group: rows wm*64 .. wm*64+63
    const int wn   = wave >> 2;       // n-group: cols wn*32 .. wn*32+31

    // ---- stage xi transposed: lds_xit[a*256 + (m>>6)*64 + (m&31)*2 + ((m>>5)&1)] ----
    {
        const int mrow  = t >> 1;
        const int chalf = (t & 1) * 32;
        const int dbase = (mrow >> 6) * 64 + (mrow & 31) * 2 + ((mrow >> 5) & 1);
        const float* src = x + (size_t)(b0 + mrow) * (NF * ND) + icol * ND + chalf;
        #pragma unroll
        for (int c = 0; c < 32; c += 4) {
            floatx4 v = *(const floatx4*)(src + c);
            lds_xit[(chalf + c + 0) * BM + dbase] = f16bits(v.x);
            lds_xit[(chalf + c + 1) * BM + dbase] = f16bits(v.y);
            lds_xit[(chalf + c + 2) * BM + dbase] = f16bits(v.z);
            lds_xit[(chalf + c + 3) * BM + dbase] = f16bits(v.w);
        }
    }

    // ---- loop-invariant xj as fp16 pairs, matching the 32x32x16 A-fragment ----
    // lane owns A[m = mt*32 + r32][k = kh*8 + j]; chunk kc covers c = kc*16 + kh*8 + j
    half2v xjh[2][16];
    #pragma unroll
    for (int mt = 0; mt < 2; ++mt) {
        const float* srow = x + (size_t)(b0 + wm*64 + mt*32 + r32) * (NF * ND)
                              + jcol * ND + kh * 8;
        #pragma unroll
        for (int kc = 0; kc < 4; ++kc) {
            floatx4 v0 = *(const floatx4*)(srow + kc * 16);
            floatx4 v1 = *(const floatx4*)(srow + kc * 16 + 4);
            xjh[mt][kc*4 + 0] = pkh2(v0.x, v0.y);
            xjh[mt][kc*4 + 1] = pkh2(v0.z, v0.w);
            xjh[mt][kc*4 + 2] = pkh2(v1.x, v1.y);
            xjh[mt][kc*4 + 3] = pkh2(v1.z, v1.w);
        }
    }

    // ---- W staging: thread (n_st = t>>3, cg = t&7) loads W[n_st][c = cg*8..+7]
    //      of cols a = 2s, 2s+1 and writes FRAGMENT layout: slab cg, row n_st ----
    const int n_st = t >> 3;
    const int cg   = t & 7;
    const float* wsrc = W + ((size_t)p * ND + n_st) * KD + cg * 8;
    uint16_t* wdst = &lds_w[cg * 512 + n_st * 8];   // + buf*WBUF + col*4096

    auto loadW2 = [&](int s2, floatx4* w) {   // global loads for stage s2 (cols 2s2, 2s2+1)
        const float* wp = wsrc + (size_t)(2 * s2) * ND;
        w[0] = *(const floatx4*)(wp);
        w[1] = *(const floatx4*)(wp + 4);
        w[2] = *(const floatx4*)(wp + ND);
        w[3] = *(const floatx4*)(wp + ND + 4);
    };
    auto packW2 = [&](int buf, const floatx4* w) {  // regs -> frag-layout LDS, 2x b128 write
        #pragma unroll
        for (int col = 0; col < 2; ++col) {
            uint4v q = (uint4v){ pk16(w[col*2].x,   w[col*2].y),   pk16(w[col*2].z,   w[col*2].w),
                                 pk16(w[col*2+1].x, w[col*2+1].y), pk16(w[col*2+1].z, w[col*2+1].w) };
            *(uint4v*)(wdst + buf * WBUF + col * 4096) = q;
        }
    };

    floatx16 acc[2] = {};    // fp32 C-accumulators, one 32x32 tile per mt
    const int rbase = kh * 512 + (wn * 32 + r32) * 8;   // lane-contiguous frag read base

// ---- one 4-MFMA group for k-chunk kc_ (A'-build is a pure producer) ----
#define MFMA4(kc_, bf0_, bf1_)                                                     \
    {                                                                              \
        union { half8 h8; half2v h2[4]; } a00, a01, a10, a11;                      \
        _Pragma("unroll")                                                          \
        for (int q = 0; q < 4; ++q) {                                              \
            const half2v xv = xjh[0][(kc_)*4 + q];                                 \
            const half2v yv = xjh[1][(kc_)*4 + q];                                 \
            a00.h2[q] = xs00 * xv;  a10.h2[q] = xs10 * xv;                         \
            a01.h2[q] = xs01 * yv;  a11.h2[q] = xs11 * yv;                         \
        }                                                                          \
        acc[0] = __builtin_amdgcn_mfma_f32_32x32x16_f16(a00.h8, bf0_, acc[0],0,0,0); \
        acc[1] = __builtin_amdgcn_mfma_f32_32x32x16_f16(a01.h8, bf0_, acc[1],0,0,0); \
        acc[0] = __builtin_amdgcn_mfma_f32_32x32x16_f16(a10.h8, bf1_, acc[0],0,0,0); \
        acc[1] = __builtin_amdgcn_mfma_f32_32x32x16_f16(a11.h8, bf1_, acc[1],0,0,0); \
    }

// ---- one stage = two sandwiched phases: {reads|prefetch, bar, lgkm0, 8 MFMA, bar} x2 ----
#define STAGE(ss_, cur_, wload_, wpack_, doload_, dopack_)                         \
    {                                                                              \
        const int a0 = 2 * (ss_);                                                  \
        const uint16_t* rb = lds_w + (cur_) * WBUF;                                \
        /* phase A: frag reads (kc 0,1) + xi + global prefetch */                  \
        if (doload_) loadW2((ss_) + 2, wload_);                                    \
        const uint32_t xi0 = *(const uint32_t*)&lds_xit[a0 * BM + wm*64 + r32*2];  \
        const uint32_t xi1 = *(const uint32_t*)&lds_xit[(a0+1) * BM + wm*64 + r32*2]; \
        half8 bA00 = *(const half8*)&rb[0*4096 + 0*1024 + rbase];                  \
        half8 bA10 = *(const half8*)&rb[1*4096 + 0*1024 + rbase];                  \
        half8 bA01 = *(const half8*)&rb[0*4096 + 1*1024 + rbase];                  \
        half8 bA11 = *(const half8*)&rb[1*4096 + 1*1024 + rbase];                  \
        const half2v xs00 = dupperm(xi0, 0x01000100u);  /* a0, mt0 */              \
        const half2v xs01 = dupperm(xi0, 0x03020302u);  /* a0, mt1 */              \
        const half2v xs10 = dupperm(xi1, 0x01000100u);  /* a1, mt0 */              \
        const half2v xs11 = dupperm(xi1, 0x03020302u);  /* a1, mt1 */              \
        barrier_only(); wait_lgkm0();                                              \
        __builtin_amdgcn_s_setprio(1);                                             \
        MFMA4(0, bA00, bA10);                                                      \
        MFMA4(1, bA01, bA11);                                                      \
        __builtin_amdgcn_s_setprio(0);                                             \
        barrier_only();                                                            \
        /* phase B: frag reads (kc 2,3) + pack next stage */                       \
        half8 bB02 = *(const half8*)&rb[0*4096 + 2*1024 + rbase];                  \
        half8 bB12 = *(const half8*)&rb[1*4096 + 2*1024 + rbase];                  \
        half8 bB03 = *(const half8*)&rb[0*4096 + 3*1024 + rbase];                  \
        half8 bB13 = *(const half8*)&rb[1*4096 + 3*1024 + rbase];                  \
        if (dopack_) packW2((cur_) ^ 1, wpack_);                                   \
        wait_lgkm0(); barrier_only();                                              \
        __builtin_amdgcn_s_setprio(1);                                             \
        MFMA4(2, bB02, bB12);                                                      \
        MFMA4(3, bB03, bB13);                                                      \
        __builtin_amdgcn_s_setprio(0);                                             \
        barrier_only();                                                            \
    }

    // ---- prologue: W(0) -> buf0; W(1) -> wr0; publish ----
    floatx4 wr0[4], wr1[4];
    loadW2(0, wr0);
    packW2(0, wr0);
    loadW2(1, wr0);        // W(1): packed at stage 0 phase B
    __syncthreads();       // one-time full barrier (xit + buf0 visible)

    // ---- main loop: 2 stages per iteration (static wr0/wr1 indexing, rule #20) ----
    #pragma unroll 1
    for (int s = 0; s < NS; s += 2) {
        STAGE(s,     0, wr1, wr0, (s + 2) < NS, true);          // load W(s+2), pack W(s+1)
        STAGE(s + 1, 1, wr0, wr1, (s + 3) < NS, (s + 2) < NS);  // load W(s+3), pack W(s+2)
    }

    // ---- epilogue: bias + store. 32x32 C/D: col = lane&31, row = (reg&3)+8*(reg>>2)+4*kh ----
    const float bb = bias[p * ND + wn*32 + r32];
    #pragma unroll
    for (int mt = 0; mt < 2; ++mt) {
        #pragma unroll
        for (int reg = 0; reg < 16; ++reg) {
            const int row = b0 + wm*64 + mt*32 + (reg & 3) + 8*(reg >> 2) + 4*kh;
            out[(size_t)row * OUT_STRIDE + p * ND + wn*32 + r32] = acc[mt][reg] + bb;
        }
    }
#undef STAGE
#undef MFMA4
}

extern "C" void kernel_launch(void* const* d_in, const int* in_sizes, int n_in,
                              void* d_out, int out_size, void* d_ws, size_t ws_size,
                              hipStream_t stream) {
    const float* x    = (const float*)d_in[0];  // (1024, 16, 64)
    const float* W    = (const float*)d_in[1];  // (120, 64, 4096)
    const float* bias = (const float*)d_in[2];  // (120, 64)
    float* out = (float*)d_out;                 // (1024, 120, 64)

    dim3 grid(NP, NB / BM);    // 480 blocks; same-p blocks land on one XCD (120 % 8 == 0)
    outer_kernel<<<grid, 512, 0, stream>>>(x, W, bias, out);
}